// Round 10
// baseline (3939.957 us; speedup 1.0000x reference)
//
#include <hip/hip_runtime.h>

#define Bq 128
#define Tq 256
#define Dq 512
#define Hq 1024
#define N4H 4096
#define KTOT 1536
#define LDW 1544   // LDS row stride in ushorts
#define NWG 128
#define NTHR 1024
#define BHq (Bq * Hq)      // one h buffer: 131072 elems
#define NHBUF (Tq + 1)     // rotating h buffers

typedef __attribute__((ext_vector_type(8))) short bf16x8;
typedef __attribute__((ext_vector_type(4))) float f32x4;

static __device__ __forceinline__ unsigned short f2bf(float x) {
    unsigned int u = __builtin_bit_cast(unsigned int, x);
    u = (u + 0x7FFFu + ((u >> 16) & 1u)) >> 16;
    return (unsigned short)u;
}
static __device__ __forceinline__ float bf2f(unsigned short h) {
    unsigned int u = ((unsigned int)h) << 16;
    return __builtin_bit_cast(float, u);
}
static __device__ __forceinline__ float sigm(float x) {
    return 1.f / (1.f + __expf(-x));
}
static __device__ __forceinline__ float tanh_f(float x) {
    return 2.f / (1.f + __expf(-2.f * x)) - 1.f;
}

// ---- pack weights: Wp[n][k] bf16, n in [0,4096), k<512 from Kw, else Rw
__global__ __launch_bounds__(256) void pack_w(const float* __restrict__ Kw,
                                              const float* __restrict__ Rw,
                                              unsigned short* __restrict__ Wp) {
    __shared__ float tile[32][33];
    int nt = blockIdx.x * 32;
    int kt = blockIdx.y * 32;
    int tx = threadIdx.x, ty = threadIdx.y;  // 32 x 8
#pragma unroll
    for (int i = 0; i < 32; i += 8) {
        int k = kt + ty + i;
        int n = nt + tx;
        float v = (k < Dq) ? Kw[(size_t)k * N4H + n] : Rw[(size_t)(k - Dq) * N4H + n];
        tile[ty + i][tx] = v;
    }
    __syncthreads();
#pragma unroll
    for (int i = 0; i < 32; i += 8) {
        int n = nt + ty + i;
        int k = kt + tx;
        Wp[(size_t)n * KTOT + k] = f2bf(tile[tx][ty + i]);
    }
}

// ---- cast + transpose input to bf16 [T][B][D]
__global__ __launch_bounds__(256) void pack_x(const float* __restrict__ X,
                                              unsigned short* __restrict__ Xb) {
    int gid = blockIdx.x * 256 + threadIdx.x;  // 2,097,152 chunks of 8
    int dc = gid & 63;
    int t = (gid >> 6) & 255;
    int b = gid >> 14;
    const float* src = X + ((size_t)b * Tq + t) * Dq + dc * 8;
    float4 v0 = *(const float4*)src;
    float4 v1 = *(const float4*)(src + 4);
    bf16x8 r;
    r[0] = (short)f2bf(v0.x); r[1] = (short)f2bf(v0.y);
    r[2] = (short)f2bf(v0.z); r[3] = (short)f2bf(v0.w);
    r[4] = (short)f2bf(v1.x); r[5] = (short)f2bf(v1.y);
    r[6] = (short)f2bf(v1.z); r[7] = (short)f2bf(v1.w);
    *(bf16x8*)(Xb + ((size_t)t * Bq + b) * Dq + dc * 8) = r;
}

// ---- zero h buffer 0 + barrier state
__global__ __launch_bounds__(256) void init_ws(unsigned short* __restrict__ Hb,
                                               unsigned* __restrict__ bar) {
    int i = blockIdx.x * 256 + threadIdx.x;  // 131072 = buffer 0 exactly
    Hb[i] = 0;
    if (i < 2048) bar[i] = 0;
}

// barrier word layout (u32 indices, 128B-separated lines):
//   xcd_cnt[x] @ x*32, topo[x] @ 512+x*32, gbar @ 1024, xflag[x] @ 1280+x*32
//
// lstm: 128 wgs x 1024 threads; wg owns 8 hidden units (32 gate-cols), all 128 rows.
// 16 waves = (rg: rows 32rg..32rg+32) x (kq: K-quarter). LDS-reduced partials.
// h exchange: WRITE-THROUGH sc1 stores to the IF$ coherence point (no wbl2),
// rotating per-step h buffers (no staleness -> no acquire). Zero cache
// maintenance ops in the whole loop.
__global__ __launch_bounds__(NTHR, 1) void lstm_persist(
    const unsigned short* __restrict__ Wp,
    const unsigned short* __restrict__ Xb,
    const float* __restrict__ bias,
    unsigned short* __restrict__ Hb,
    const float* __restrict__ dw,
    const float* __restrict__ db,
    float* __restrict__ out,
    unsigned* __restrict__ bar) {
    extern __shared__ unsigned short Wl[];  // 32*LDW ushorts (98,816 B) + 49,152 B redbuf
    float* redbuf = (float*)(Wl + 32 * LDW);
    __shared__ float red[16];
    __shared__ int s_topo[3];  // myxcd, mytot, nxcd

    const int wg = blockIdx.x;
    const int hs0 = wg * 8;
    const int tid = threadIdx.x;
    const int wave = tid >> 6;
    const int lane = tid & 63;
    const int rg = wave & 3;    // row group: rows [32rg, 32rg+32)
    const int kq = wave >> 2;   // K quarter
    const int rowb = rg * 32;
    const int c16 = lane & 15;
    const int kg = lane >> 4;

    // ---- startup: discover physical XCD topology (pure relaxed atomics)
    if (tid == 0) {
        int xcd;
        asm volatile("s_getreg_b32 %0, hwreg(HW_REG_XCC_ID)" : "=s"(xcd));
        xcd &= 15;
        __hip_atomic_fetch_add(&bar[512 + xcd * 32], 1u, __ATOMIC_RELAXED, __HIP_MEMORY_SCOPE_AGENT);
        for (;;) {
            unsigned sum = 0;
            for (int i = 0; i < 16; ++i)
                sum += __hip_atomic_load(&bar[512 + i * 32], __ATOMIC_RELAXED, __HIP_MEMORY_SCOPE_AGENT);
            if (sum == NWG) break;
            __builtin_amdgcn_s_sleep(2);
        }
        int nx = 0, tot = 0;
        for (int i = 0; i < 16; ++i) {
            unsigned v = __hip_atomic_load(&bar[512 + i * 32], __ATOMIC_RELAXED, __HIP_MEMORY_SCOPE_AGENT);
            if (v) nx++;
            if (i == xcd) tot = (int)v;
        }
        s_topo[0] = xcd;
        s_topo[1] = tot;
        s_topo[2] = nx;
    }

    // load this wg's 32 weight columns into LDS (once)
    for (int c = tid; c < 32 * 192; c += NTHR) {
        int lc = c / 192;   // local col: q*8+u
        int pos = c % 192;  // bf16x8 chunk within row
        int q = lc >> 3, u = lc & 7;
        bf16x8 v = *(const bf16x8*)(Wp + (size_t)(q * Hq + hs0 + u) * KTOT + pos * 8);
        *(bf16x8*)(&Wl[lc * LDW + pos * 8]) = v;
    }

    const int col0 = (c16 >> 3) * Hq + hs0 + (c16 & 7);
    const int col1 = ((c16 >> 3) + 2) * Hq + hs0 + (c16 & 7);
    const float bias0 = bias[col0];
    const float bias1 = bias[col1];
    const bool hi = (c16 & 8) != 0;
    const int j = hs0 + (c16 & 7);
    const int arow0 = rowb + c16;
    const int arow1 = arow0 + 16;
    const int wl0 = c16 * LDW + kg * 8;
    const int wl1 = (16 + c16) * LDW + kg * 8;
    // this wave's K slices
    const int xoff = kq * 128 + kg * 8;        // x K-quarter (of 512)
    const int hoff = kq * 256 + kg * 8;        // h K-quarter (of 1024)
    const int rbase = (((kq - 1) * 4 + rg) * 64 + lane) * 16;  // redbuf slot (kq>=1)
    float* myred = &redbuf[((kq ? rbase : 0))];

    float creg[8];
#pragma unroll
    for (int i = 0; i < 8; ++i) creg[i] = 0.f;

    __syncthreads();
    const int myxcd = s_topo[0];
    const unsigned mytot = (unsigned)s_topo[1];
    const unsigned nxcd = (unsigned)s_topo[2];

    // x-part partial accumulators for step 0 (this wave's K-quarter)
    f32x4 xa00 = {0.f, 0.f, 0.f, 0.f};
    f32x4 xa01 = {0.f, 0.f, 0.f, 0.f};
    f32x4 xa10 = {0.f, 0.f, 0.f, 0.f};
    f32x4 xa11 = {0.f, 0.f, 0.f, 0.f};
    {
        const unsigned short* xr0 = Xb + (size_t)arow0 * Dq + xoff;
        const unsigned short* xr1 = Xb + (size_t)arow1 * Dq + xoff;
#pragma unroll
        for (int kc = 0; kc < 4; ++kc) {
            bf16x8 a0 = *(const bf16x8*)(xr0 + kc * 32);
            bf16x8 a1 = *(const bf16x8*)(xr1 + kc * 32);
            bf16x8 b0 = *(const bf16x8*)(&Wl[wl0 + kq * 128 + kc * 32]);
            bf16x8 b1 = *(const bf16x8*)(&Wl[wl1 + kq * 128 + kc * 32]);
            xa00 = __builtin_amdgcn_mfma_f32_16x16x32_bf16(a0, b0, xa00, 0, 0, 0);
            xa01 = __builtin_amdgcn_mfma_f32_16x16x32_bf16(a0, b1, xa01, 0, 0, 0);
            xa10 = __builtin_amdgcn_mfma_f32_16x16x32_bf16(a1, b0, xa10, 0, 0, 0);
            xa11 = __builtin_amdgcn_mfma_f32_16x16x32_bf16(a1, b1, xa11, 0, 0, 0);
        }
    }

    for (int t = 0; t < Tq; ++t) {
        // rotating buffers: read h_t from buf[t], write h_{t+1} to buf[t+1]
        const unsigned short* Hcur = Hb + (size_t)t * BHq;
        unsigned short* Hnxt = Hb + (size_t)(t + 1) * BHq;

        const unsigned short* hr0 = Hcur + (size_t)arow0 * Hq + hoff;
        const unsigned short* hr1 = Hcur + (size_t)arow1 * Hq + hoff;

        f32x4 acc00 = xa00, acc01 = xa01, acc10 = xa10, acc11 = xa11;

        // h-part GEMM over this wave's K-quarter (8 kc iterations)
#pragma unroll
        for (int kc = 0; kc < 8; ++kc) {
            bf16x8 a0 = *(const bf16x8*)(hr0 + kc * 32);
            bf16x8 a1 = *(const bf16x8*)(hr1 + kc * 32);
            bf16x8 b0 = *(const bf16x8*)(&Wl[wl0 + 512 + kq * 256 + kc * 32]);
            bf16x8 b1 = *(const bf16x8*)(&Wl[wl1 + 512 + kq * 256 + kc * 32]);
            acc00 = __builtin_amdgcn_mfma_f32_16x16x32_bf16(a0, b0, acc00, 0, 0, 0);
            acc01 = __builtin_amdgcn_mfma_f32_16x16x32_bf16(a0, b1, acc01, 0, 0, 0);
            acc10 = __builtin_amdgcn_mfma_f32_16x16x32_bf16(a1, b0, acc10, 0, 0, 0);
            acc11 = __builtin_amdgcn_mfma_f32_16x16x32_bf16(a1, b1, acc11, 0, 0, 0);
        }

        // partial-acc write (kq>=1)
        if (kq) {
            *(f32x4*)&myred[0] = acc00;
            *(f32x4*)&myred[4] = acc01;
            *(f32x4*)&myred[8] = acc10;
            *(f32x4*)&myred[12] = acc11;
        }
        __syncthreads();  // (A) partials visible

        if (kq == 0) {
            // reduce + epilogue + WRITE-THROUGH h store (sc1 -> IF$, no wbl2 needed)
#pragma unroll
            for (int kqi = 1; kqi < 4; ++kqi) {
                const float* rb = &redbuf[(((kqi - 1) * 4 + rg) * 64 + lane) * 16];
                acc00 += *(const f32x4*)&rb[0];
                acc01 += *(const f32x4*)&rb[4];
                acc10 += *(const f32x4*)&rb[8];
                acc11 += *(const f32x4*)&rb[12];
            }
#pragma unroll
            for (int m = 0; m < 2; ++m) {
                f32x4 z0 = m ? acc10 : acc00;
                f32x4 z1 = m ? acc11 : acc01;
#pragma unroll
                for (int r = 0; r < 4; ++r) {
                    float za = z0[r] + bias0;
                    float zb = z1[r] + bias1;
                    float pa = __shfl_xor(za, 8, 64);
                    float pb = __shfl_xor(zb, 8, 64);
                    float zi = hi ? pa : za;
                    float zf = hi ? za : pa;
                    float zg = hi ? pb : zb;
                    float zo = hi ? zb : pb;
                    float gi = sigm(zi);
                    float gf = sigm(zf);
                    float go = sigm(zo);
                    float gg = tanh_f(zg);
                    float cn = gf * creg[m * 4 + r] + gi * gg;
                    creg[m * 4 + r] = cn;
                    float hn = go * tanh_f(cn);
                    // pair adjacent j (c16 even/odd) -> one 4B sc1 store
                    unsigned hb16 = (unsigned)f2bf(hn);
                    unsigned pv = (unsigned)__shfl_xor((int)hb16, 1, 64);
                    unsigned word = (c16 & 1) ? ((pv & 0xffffu) | (hb16 << 16))
                                              : ((hb16 & 0xffffu) | (pv << 16));
                    if (!hi && (c16 & 1) == m) {
                        int b = rowb + m * 16 + kg * 4 + r;
                        __hip_atomic_store((unsigned*)(Hnxt + (size_t)b * Hq + (j & ~1)), word,
                                           __ATOMIC_RELAXED, __HIP_MEMORY_SCOPE_AGENT);
                    }
                }
            }
        } else if (t + 1 < Tq) {
            // overlap with kq0's epilogue: x-part GEMM for step t+1
            const unsigned short* xr0 = Xb + ((size_t)(t + 1) * Bq + arow0) * Dq + xoff;
            const unsigned short* xr1 = Xb + ((size_t)(t + 1) * Bq + arow1) * Dq + xoff;
            xa00 = (f32x4){0.f, 0.f, 0.f, 0.f};
            xa01 = (f32x4){0.f, 0.f, 0.f, 0.f};
            xa10 = (f32x4){0.f, 0.f, 0.f, 0.f};
            xa11 = (f32x4){0.f, 0.f, 0.f, 0.f};
#pragma unroll
            for (int kc = 0; kc < 4; ++kc) {
                bf16x8 a0 = *(const bf16x8*)(xr0 + kc * 32);
                bf16x8 a1 = *(const bf16x8*)(xr1 + kc * 32);
                bf16x8 b0 = *(const bf16x8*)(&Wl[wl0 + kq * 128 + kc * 32]);
                bf16x8 b1 = *(const bf16x8*)(&Wl[wl1 + kq * 128 + kc * 32]);
                xa00 = __builtin_amdgcn_mfma_f32_16x16x32_bf16(a0, b0, xa00, 0, 0, 0);
                xa01 = __builtin_amdgcn_mfma_f32_16x16x32_bf16(a0, b1, xa01, 0, 0, 0);
                xa10 = __builtin_amdgcn_mfma_f32_16x16x32_bf16(a1, b0, xa10, 0, 0, 0);
                xa11 = __builtin_amdgcn_mfma_f32_16x16x32_bf16(a1, b1, xa11, 0, 0, 0);
            }
        }

        __syncthreads();  // (B) all h sc1 stores acked at IF$ (vmcnt drain) -> visible device-wide

        // ---- arrive: per-XCD counter; last-on-XCD bumps global; last globally
        // fan-outs step flags. NO fences.
        if (tid == 0) {
            unsigned old = __hip_atomic_fetch_add(&bar[myxcd * 32], 1u,
                                                  __ATOMIC_RELAXED, __HIP_MEMORY_SCOPE_AGENT);
            if (old == (unsigned)(t + 1) * mytot - 1u) {
                unsigned gold = __hip_atomic_fetch_add(&bar[1024], 1u,
                                                       __ATOMIC_RELAXED, __HIP_MEMORY_SCOPE_AGENT);
                if (gold == (unsigned)(t + 1) * nxcd - 1u) {
#pragma unroll
                    for (int x = 0; x < 16; ++x)
                        __hip_atomic_store(&bar[1280 + x * 32], (unsigned)(t + 1),
                                           __ATOMIC_RELAXED, __HIP_MEMORY_SCOPE_AGENT);
                }
            }
        }

        // kq0 waves: x-part GEMM for t+1 (overlaps barrier wait)
        if (kq == 0 && t + 1 < Tq) {
            const unsigned short* xr0 = Xb + ((size_t)(t + 1) * Bq + arow0) * Dq + xoff;
            const unsigned short* xr1 = Xb + ((size_t)(t + 1) * Bq + arow1) * Dq + xoff;
            xa00 = (f32x4){0.f, 0.f, 0.f, 0.f};
            xa01 = (f32x4){0.f, 0.f, 0.f, 0.f};
            xa10 = (f32x4){0.f, 0.f, 0.f, 0.f};
            xa11 = (f32x4){0.f, 0.f, 0.f, 0.f};
#pragma unroll
            for (int kc = 0; kc < 4; ++kc) {
                bf16x8 a0 = *(const bf16x8*)(xr0 + kc * 32);
                bf16x8 a1 = *(const bf16x8*)(xr1 + kc * 32);
                bf16x8 b0 = *(const bf16x8*)(&Wl[wl0 + kc * 32]);  // kq==0
                bf16x8 b1 = *(const bf16x8*)(&Wl[wl1 + kc * 32]);
                xa00 = __builtin_amdgcn_mfma_f32_16x16x32_bf16(a0, b0, xa00, 0, 0, 0);
                xa01 = __builtin_amdgcn_mfma_f32_16x16x32_bf16(a0, b1, xa01, 0, 0, 0);
                xa10 = __builtin_amdgcn_mfma_f32_16x16x32_bf16(a1, b0, xa10, 0, 0, 0);
                xa11 = __builtin_amdgcn_mfma_f32_16x16x32_bf16(a1, b1, xa11, 0, 0, 0);
            }
        }

        // ---- wait: poll only this XCD's flag line. No acquire: rotating h
        // buffers are never stale in any cache.
        if (tid == 0) {
            while (__hip_atomic_load(&bar[1280 + myxcd * 32], __ATOMIC_RELAXED,
                                     __HIP_MEMORY_SCOPE_AGENT) < (unsigned)(t + 1)) {
                __builtin_amdgcn_s_sleep(4);
            }
            asm volatile("" ::: "memory");
        }
        __syncthreads();  // (C)
    }

    // dense head: wg handles batch row b = wg; final h is buffer Tq (=256)
    {
        const unsigned short* hl = Hb + (size_t)Tq * BHq + (size_t)wg * Hq;
        float s = bf2f(hl[tid]) * dw[tid];  // Hq == NTHR
#pragma unroll
        for (int off = 32; off > 0; off >>= 1) s += __shfl_down(s, off, 64);
        if (lane == 0) red[wave] = s;
        __syncthreads();
        if (tid == 0) {
            float tot = db[0];
#pragma unroll
            for (int wv = 0; wv < 16; ++wv) tot += red[wv];
            out[wg] = 1.f / (1.f + __expf(-tot));
        }
    }
}

extern "C" void kernel_launch(void* const* d_in, const int* in_sizes, int n_in,
                              void* d_out, int out_size, void* d_ws, size_t ws_size,
                              hipStream_t stream) {
    const float* X = (const float*)d_in[0];
    const float* Kw = (const float*)d_in[1];
    const float* Rw = (const float*)d_in[2];
    const float* bias = (const float*)d_in[3];
    const float* dw = (const float*)d_in[4];
    const float* db = (const float*)d_in[5];
    float* out = (float*)d_out;
    char* ws = (char*)d_ws;

    // workspace layout:
    //   Wp  bf16 [4096][1536]       @ 0          (12,582,912)
    //   Xb  bf16 [256][128][512]    @ 12,582,912 (33,554,432)   [T][B][D]
    //   Hb  bf16 [257][128][1024]   @ 46,137,344 (67,371,008)   rotating
    //   bar u32  [2048]             @ 113,508,352 (8,192)       total ~113.5 MB
    unsigned short* Wp = (unsigned short*)(ws);
    unsigned short* Xb = (unsigned short*)(ws + 12582912);
    unsigned short* Hb = (unsigned short*)(ws + 46137344);
    unsigned* bar = (unsigned*)(ws + 113508352);

    pack_w<<<dim3(128, 48), dim3(32, 8), 0, stream>>>(Kw, Rw, Wp);
    pack_x<<<8192, 256, 0, stream>>>(X, Xb);
    init_ws<<<512, 256, 0, stream>>>(Hb, bar);

    size_t lds_bytes = (size_t)32 * LDW * sizeof(unsigned short) + 49152;  // 147,968
    lstm_persist<<<NWG, NTHR, lds_bytes, stream>>>(Wp, Xb, bias, Hb, dw, db, out, bar);
}

// Round 11
// 3269.956 us; speedup vs baseline: 1.2049x; 1.2049x over previous
//
#include <hip/hip_runtime.h>

#define Bq 128
#define Tq 256
#define Dq 512
#define Hq 1024
#define N4H 4096
#define NWG 256          // 1 wg per CU, 32 per XCD (forced by 147KB LDS)
#define NTHR 1024        // 16 waves: (ug in [0,4)) x (kq in [0,4))
#define BHq (Bq * Hq)

typedef __attribute__((ext_vector_type(8))) short bf16x8;
typedef __attribute__((ext_vector_type(4))) float f32x4;

static __device__ __forceinline__ unsigned short f2bf(float x) {
    unsigned int u = __builtin_bit_cast(unsigned int, x);
    u = (u + 0x7FFFu + ((u >> 16) & 1u)) >> 16;
    return (unsigned short)u;
}
static __device__ __forceinline__ float bf2f(unsigned short h) {
    unsigned int u = ((unsigned int)h) << 16;
    return __builtin_bit_cast(float, u);
}
static __device__ __forceinline__ float sigm(float x) { return 1.f / (1.f + __expf(-x)); }
static __device__ __forceinline__ float tanh_f(float x) { return 2.f / (1.f + __expf(-2.f * x)) - 1.f; }

// ---- pack weights into MFMA-fragment order:
// Wp[s][c][wlc][kg][8e]  (ushort offset = (((s*48+c)*128+wlc)*4+kg)*8)
//   s   = unit-group (wg slot) in [0,32)   : hidden units [32s, 32s+32)
//   c   = K-chunk in [0,48)                : k in [32c, 32c+32); k<512 = x-part (Kw), else h-part (Rw)
//   wlc = q*32+u (gate q, unit u in [0,32))
//   kg  = k-subgroup in [0,4), e = k element
__global__ __launch_bounds__(256) void pack_w(const float* __restrict__ Kw,
                                              const float* __restrict__ Rw,
                                              unsigned short* __restrict__ Wp) {
    __shared__ float tile[32][33];
    int n0 = blockIdx.x * 32;  // gate-col base (32-aligned, single (s,q))
    int k0 = blockIdx.y * 32;  // K base (single chunk c)
    int tx = threadIdx.x, ty = threadIdx.y;  // 32 x 8
#pragma unroll
    for (int i = 0; i < 32; i += 8) {
        int k = k0 + ty + i;
        float v = (k < Dq) ? Kw[(size_t)k * N4H + n0 + tx] : Rw[(size_t)(k - Dq) * N4H + n0 + tx];
        tile[ty + i][tx] = v;
    }
    __syncthreads();
    if (ty < 4) {
        int s = (n0 & 1023) >> 5;
        int q = n0 >> 10;
        int c = k0 >> 5;
        int wlc = q * 32 + tx;
        bf16x8 v;
#pragma unroll
        for (int e = 0; e < 8; ++e) v[e] = (short)f2bf(tile[ty * 8 + e][tx]);
        *(bf16x8*)(Wp + ((((size_t)s * 48 + c) * 128 + wlc) * 4 + ty) * 8) = v;
    }
}

// ---- cast + transpose input to bf16 [T][B][D]
__global__ __launch_bounds__(256) void pack_x(const float* __restrict__ X,
                                              unsigned short* __restrict__ Xb) {
    int gid = blockIdx.x * 256 + threadIdx.x;
    int dc = gid & 63;
    int t = (gid >> 6) & 255;
    int b = gid >> 14;
    const float* src = X + ((size_t)b * Tq + t) * Dq + dc * 8;
    float4 v0 = *(const float4*)src;
    float4 v1 = *(const float4*)(src + 4);
    bf16x8 r;
    r[0] = (short)f2bf(v0.x); r[1] = (short)f2bf(v0.y);
    r[2] = (short)f2bf(v0.z); r[3] = (short)f2bf(v0.w);
    r[4] = (short)f2bf(v1.x); r[5] = (short)f2bf(v1.y);
    r[6] = (short)f2bf(v1.z); r[7] = (short)f2bf(v1.w);
    *(bf16x8*)(Xb + ((size_t)t * Bq + b) * Dq + dc * 8) = r;
}

// ---- zero h buffer 0 + barrier/topology state (re-run every launch: graph-replay safe)
__global__ __launch_bounds__(256) void init_ws(unsigned short* __restrict__ Hb,
                                               unsigned* __restrict__ bar) {
    int i = blockIdx.x * 256 + threadIdx.x;  // 131072 = h buffer 0
    Hb[i] = 0;
    if (i < 2048) bar[i] = 0;
}

// bar layout (u32, 128B-separated lines):
//   cnt[x]  @ x*32        : per-XCD step counter (PLAIN atomics -> executes in local L2)
//   topo[x] @ 512 + x*32  : registration/slot tickets (AGENT atomics -> IF$, one-time)
__global__ __launch_bounds__(NTHR, 1) void lstm_persist(
    const unsigned short* __restrict__ Wp,
    const unsigned short* __restrict__ Xb,
    const float* __restrict__ bias,
    unsigned short* __restrict__ Hb,
    const float* __restrict__ dw,
    const float* __restrict__ db,
    float* __restrict__ out,
    unsigned* __restrict__ bar) {
    // LDS: weights chunks 16..27 (K [512,896)), padded: [(cc*128+wlc)*40 + kg*8]
    //      122,880 B + redbuf 24,576 B = 147,456 B  (forces 1 wg/CU -> 32 wg/XCD)
    extern __shared__ unsigned short Wl[];
    float* redbuf = (float*)(Wl + 61440);
    __shared__ float red[16];
    __shared__ int s_topo[4];  // slot, rbase, myxcd, mytot

    const int tid = threadIdx.x;
    const int wave = tid >> 6;
    const int lane = tid & 63;
    const int ug = wave & 3;   // unit-group: units [8ug, 8ug+8) within the wg's 32
    const int kq = wave >> 2;  // K-interleave class: chunks c = kq + 4i
    const int c16 = lane & 15;
    const int kg = lane >> 4;

    // ---- startup: XCD topology + slot ticket (agent scope, one-time)
    if (tid == 0) {
        int xcd;
        asm volatile("s_getreg_b32 %0, hwreg(HW_REG_XCC_ID)" : "=s"(xcd));
        xcd &= 15;
        unsigned slot = __hip_atomic_fetch_add(&bar[512 + xcd * 32], 1u,
                                               __ATOMIC_RELAXED, __HIP_MEMORY_SCOPE_AGENT);
        for (;;) {
            unsigned sum = 0;
            for (int i = 0; i < 16; ++i)
                sum += __hip_atomic_load(&bar[512 + i * 32], __ATOMIC_RELAXED, __HIP_MEMORY_SCOPE_AGENT);
            if (sum == NWG) break;
            __builtin_amdgcn_s_sleep(2);
        }
        int rank = 0, nx = 0, tot = 0;
        for (int i = 0; i < 16; ++i) {
            unsigned v = __hip_atomic_load(&bar[512 + i * 32], __ATOMIC_RELAXED, __HIP_MEMORY_SCOPE_AGENT);
            if (v) { if (i < xcd) rank++; nx++; }
            if (i == xcd) tot = (int)v;
        }
        s_topo[0] = (int)slot;
        s_topo[1] = rank * (Bq / nx);  // 16 rows per XCD when nx==8
        s_topo[2] = xcd;
        s_topo[3] = tot;
    }
    __syncthreads();
    const int slot = s_topo[0];
    const int rbase = s_topo[1];
    const int myxcd = s_topo[2];
    const unsigned mytot = (unsigned)s_topo[3];

    const size_t gbase = (size_t)slot * 48 * 4096;  // this wg's weight block (ushorts)

    // ---- load LDS weight chunks 16..27 (6144 fragments of 16B)
    for (int it = tid; it < 6144; it += NTHR) {
        int kgx = it & 3;
        int wlcx = (it >> 2) & 127;
        int cc = it >> 9;  // 0..11
        *(bf16x8*)(Wl + ((cc * 128 + wlcx) * 40 + kgx * 8)) =
            *(const bf16x8*)(Wp + gbase + (size_t)(16 + cc) * 4096 + ((size_t)wlcx * 4 + kgx) * 8);
    }

    // per-lane constants (identical math to the verified r8/r10 epilogue, 16-row block)
    const int wlc0 = (c16 >> 3) * 32 + ug * 8 + (c16 & 7);
    const int wlc1 = wlc0 + 64;
    const int col0 = (c16 >> 3) * Hq + slot * 32 + ug * 8 + (c16 & 7);
    const int col1 = col0 + 2 * Hq;
    const float bias0 = bias[col0];
    const float bias1 = bias[col1];
    const bool hi = (c16 & 8) != 0;
    const int j = slot * 32 + ug * 8 + (c16 & 7);
    const int arow = rbase + c16;

    float creg[4];
#pragma unroll
    for (int i = 0; i < 4; ++i) creg[i] = 0.f;

    __syncthreads();

    // ---- x-part partial accs for t=0 (this wave's 4 x-chunks, streamed weights)
    f32x4 xa0 = {0.f, 0.f, 0.f, 0.f};
    f32x4 xa1 = {0.f, 0.f, 0.f, 0.f};
    {
        const unsigned short* xb = Xb + (size_t)arow * Dq + kg * 8;
#pragma unroll
        for (int i = 0; i < 4; ++i) {
            int c = kq + 4 * i;
            bf16x8 A = *(const bf16x8*)(xb + c * 32);
            const unsigned short* gp = Wp + gbase + (size_t)c * 4096;
            bf16x8 B0 = *(const bf16x8*)(gp + (wlc0 * 4 + kg) * 8);
            bf16x8 B1 = *(const bf16x8*)(gp + (wlc1 * 4 + kg) * 8);
            xa0 = __builtin_amdgcn_mfma_f32_16x16x32_bf16(A, B0, xa0, 0, 0, 0);
            xa1 = __builtin_amdgcn_mfma_f32_16x16x32_bf16(A, B1, xa1, 0, 0, 0);
        }
    }

    const unsigned long long cntaddr = (unsigned long long)(bar + myxcd * 32);

    for (int t = 0; t < Tq; ++t) {
        const unsigned short* Hcur = Hb + (size_t)t * BHq;
        unsigned short* Hnxt = Hb + (size_t)(t + 1) * BHq;
        const unsigned short* hb = Hcur + (size_t)arow * Hq + kg * 8;

        f32x4 acc0 = xa0, acc1 = xa1;

        // h-part GEMM: streamed chunks (i 7..11, K [896,1536) slice) + LDS chunks (i 4..6)
#pragma unroll
        for (int i = 7; i < 12; ++i) {
            int c = kq + 4 * i;
            bf16x8 A = *(const bf16x8*)(hb + (c * 32 - Dq));
            const unsigned short* gp = Wp + gbase + (size_t)c * 4096;
            bf16x8 B0 = *(const bf16x8*)(gp + (wlc0 * 4 + kg) * 8);
            bf16x8 B1 = *(const bf16x8*)(gp + (wlc1 * 4 + kg) * 8);
            acc0 = __builtin_amdgcn_mfma_f32_16x16x32_bf16(A, B0, acc0, 0, 0, 0);
            acc1 = __builtin_amdgcn_mfma_f32_16x16x32_bf16(A, B1, acc1, 0, 0, 0);
        }
#pragma unroll
        for (int i = 4; i < 7; ++i) {
            int c = kq + 4 * i;
            bf16x8 A = *(const bf16x8*)(hb + (c * 32 - Dq));
            const unsigned short* lp = Wl + ((c - 16) * 128) * 40 + kg * 8;
            bf16x8 B0 = *(const bf16x8*)(lp + wlc0 * 40);
            bf16x8 B1 = *(const bf16x8*)(lp + wlc1 * 40);
            acc0 = __builtin_amdgcn_mfma_f32_16x16x32_bf16(A, B0, acc0, 0, 0, 0);
            acc1 = __builtin_amdgcn_mfma_f32_16x16x32_bf16(A, B1, acc1, 0, 0, 0);
        }

        if (kq) {
            float* mr = redbuf + (((kq - 1) * 4 + ug) * 64 + lane) * 8;
            *(f32x4*)&mr[0] = acc0;
            *(f32x4*)&mr[4] = acc1;
        }
        __syncthreads();  // (A) partials visible in LDS

        if (kq == 0) {
#pragma unroll
            for (int kqi = 1; kqi < 4; ++kqi) {
                const float* rb = redbuf + (((kqi - 1) * 4 + ug) * 64 + lane) * 8;
                acc0 += *(const f32x4*)&rb[0];
                acc1 += *(const f32x4*)&rb[4];
            }
#pragma unroll
            for (int r = 0; r < 4; ++r) {
                float za = acc0[r] + bias0;
                float zb = acc1[r] + bias1;
                float pa = __shfl_xor(za, 8, 64);
                float pb = __shfl_xor(zb, 8, 64);
                float zi = hi ? pa : za;
                float zf = hi ? za : pa;
                float zg = hi ? pb : zb;
                float zo = hi ? zb : pb;
                float gi = sigm(zi);
                float gf = sigm(zf);
                float go = sigm(zo);
                float gg = tanh_f(zg);
                float cn = gf * creg[r] + gi * gg;
                creg[r] = cn;
                float hn = go * tanh_f(cn);
                unsigned hb16 = (unsigned)f2bf(hn);
                unsigned pv = (unsigned)__shfl_xor((int)hb16, 1, 64);
                if (!hi && !(c16 & 1)) {
                    unsigned word = (hb16 & 0xffffu) | (pv << 16);
                    int b = rbase + kg * 4 + r;
                    unsigned long long a = (unsigned long long)(Hnxt + (size_t)b * Hq + j);
                    // sc0 store: write-through L1 into the XCD's L2 (intra-XCD visibility)
                    asm volatile("global_store_dword %0, %1, off sc0" ::"v"(a), "v"(word) : "memory");
                }
            }
        } else if (t + 1 < Tq) {
            // overlap kq0's epilogue: x-part prefetch for t+1
            const unsigned short* xb = Xb + ((size_t)(t + 1) * Bq + arow) * Dq + kg * 8;
            xa0 = (f32x4){0.f, 0.f, 0.f, 0.f};
            xa1 = (f32x4){0.f, 0.f, 0.f, 0.f};
#pragma unroll
            for (int i = 0; i < 4; ++i) {
                int c = kq + 4 * i;
                bf16x8 A = *(const bf16x8*)(xb + c * 32);
                const unsigned short* gp = Wp + gbase + (size_t)c * 4096;
                bf16x8 B0 = *(const bf16x8*)(gp + (wlc0 * 4 + kg) * 8);
                bf16x8 B1 = *(const bf16x8*)(gp + (wlc1 * 4 + kg) * 8);
                xa0 = __builtin_amdgcn_mfma_f32_16x16x32_bf16(A, B0, xa0, 0, 0, 0);
                xa1 = __builtin_amdgcn_mfma_f32_16x16x32_bf16(A, B1, xa1, 0, 0, 0);
            }
        }

        __syncthreads();  // (B) all waves' h-stores drained (vmcnt(0)) -> committed in local L2

        // ---- arrive: PLAIN atomic add (executes at this XCD's L2; line is XCD-private)
        if (tid == 0) {
            asm volatile("global_atomic_add %0, %1, off" ::"v"(cntaddr), "v"(1u) : "memory");
        }

        // kq0 waves: x-part prefetch for t+1 (overlaps barrier wait)
        if (kq == 0 && t + 1 < Tq) {
            const unsigned short* xb = Xb + ((size_t)(t + 1) * Bq + arow) * Dq + kg * 8;
            xa0 = (f32x4){0.f, 0.f, 0.f, 0.f};
            xa1 = (f32x4){0.f, 0.f, 0.f, 0.f};
#pragma unroll
            for (int i = 0; i < 4; ++i) {
                int c = kq + 4 * i;
                bf16x8 A = *(const bf16x8*)(xb + c * 32);
                const unsigned short* gp = Wp + gbase + (size_t)c * 4096;
                bf16x8 B0 = *(const bf16x8*)(gp + (wlc0 * 4 + kg) * 8);
                bf16x8 B1 = *(const bf16x8*)(gp + (wlc1 * 4 + kg) * 8);
                xa0 = __builtin_amdgcn_mfma_f32_16x16x32_bf16(A, B0, xa0, 0, 0, 0);
                xa1 = __builtin_amdgcn_mfma_f32_16x16x32_bf16(A, B1, xa1, 0, 0, 0);
            }
        }

        // ---- wait: atomic-add-0 read of the counter (L2-executed RMW = always fresh,
        // immune to L1 staleness). No fences anywhere in the loop.
        if (tid == 0) {
            const unsigned target = mytot * (unsigned)(t + 1);
            for (;;) {
                unsigned old;
                asm volatile("global_atomic_add %0, %1, %2, off sc0\n\ts_waitcnt vmcnt(0)"
                             : "=v"(old)
                             : "v"(cntaddr), "v"(0u)
                             : "memory");
                if (old >= target) break;
                __builtin_amdgcn_s_sleep(1);
            }
        }
        __syncthreads();  // (C)
    }

    // ---- dense head: slots 0..15 each handle one local batch row (local-L2 reads)
    if (slot < 16) {
        const int b = rbase + slot;
        const unsigned short* hl = Hb + (size_t)Tq * BHq + (size_t)b * Hq;
        float s = bf2f(hl[tid]) * dw[tid];  // Hq == NTHR
#pragma unroll
        for (int off = 32; off > 0; off >>= 1) s += __shfl_down(s, off, 64);
        if (lane == 0) red[wave] = s;
        __syncthreads();
        if (tid == 0) {
            float tot = db[0];
#pragma unroll
            for (int wv = 0; wv < 16; ++wv) tot += red[wv];
            out[b] = 1.f / (1.f + __expf(-tot));
        }
    }
}

extern "C" void kernel_launch(void* const* d_in, const int* in_sizes, int n_in,
                              void* d_out, int out_size, void* d_ws, size_t ws_size,
                              hipStream_t stream) {
    const float* X = (const float*)d_in[0];
    const float* Kw = (const float*)d_in[1];
    const float* Rw = (const float*)d_in[2];
    const float* bias = (const float*)d_in[3];
    const float* dw = (const float*)d_in[4];
    const float* db = (const float*)d_in[5];
    float* out = (float*)d_out;
    char* ws = (char*)d_ws;

    // workspace layout:
    //   Wp  bf16 fragment-packed [32][48][128][4][8]  @ 0           (12,582,912)
    //   Xb  bf16 [256][128][512]                      @ 12,582,912  (33,554,432)
    //   Hb  bf16 [257][128][1024] rotating            @ 46,137,344  (67,371,008)
    //   bar u32 [2048]                                @ 113,508,352 (8,192)
    unsigned short* Wp = (unsigned short*)(ws);
    unsigned short* Xb = (unsigned short*)(ws + 12582912);
    unsigned short* Hb = (unsigned short*)(ws + 46137344);
    unsigned* bar = (unsigned*)(ws + 113508352);

    pack_w<<<dim3(128, 48), dim3(32, 8), 0, stream>>>(Kw, Rw, Wp);
    pack_x<<<8192, 256, 0, stream>>>(X, Xb);
    init_ws<<<512, 256, 0, stream>>>(Hb, bar);

    size_t lds_bytes = 147456;  // 122,880 weights + 24,576 redbuf
    lstm_persist<<<NWG, NTHR, lds_bytes, stream>>>(Wp, Xb, bias, Hb, dw, db, out, bar);
}

// Round 12
// 3123.407 us; speedup vs baseline: 1.2614x; 1.0469x over previous
//
#include <hip/hip_runtime.h>

#define Bq 128
#define Tq 256
#define Dq 512
#define Hq 1024
#define N4H 4096
#define NWG 256          // 1 wg per CU, 32 per XCD (forced by 147KB LDS)
#define NTHR 1024        // 16 waves: (ug in [0,4)) x (kq in [0,4))
#define BHq (Bq * Hq)

typedef __attribute__((ext_vector_type(8))) short bf16x8;
typedef __attribute__((ext_vector_type(4))) float f32x4;

static __device__ __forceinline__ unsigned short f2bf(float x) {
    unsigned int u = __builtin_bit_cast(unsigned int, x);
    u = (u + 0x7FFFu + ((u >> 16) & 1u)) >> 16;
    return (unsigned short)u;
}
static __device__ __forceinline__ float bf2f(unsigned short h) {
    unsigned int u = ((unsigned int)h) << 16;
    return __builtin_bit_cast(float, u);
}
static __device__ __forceinline__ float sigm(float x) { return 1.f / (1.f + __expf(-x)); }
static __device__ __forceinline__ float tanh_f(float x) { return 2.f / (1.f + __expf(-2.f * x)) - 1.f; }

// ---- pack weights into MFMA-fragment order:
// Wp[s][c][wlc][kg][8e]  (ushort offset = (((s*48+c)*128+wlc)*4+kg)*8)
__global__ __launch_bounds__(256) void pack_w(const float* __restrict__ Kw,
                                              const float* __restrict__ Rw,
                                              unsigned short* __restrict__ Wp) {
    __shared__ float tile[32][33];
    int n0 = blockIdx.x * 32;  // gate-col base
    int k0 = blockIdx.y * 32;  // K base
    int tx = threadIdx.x, ty = threadIdx.y;  // 32 x 8
#pragma unroll
    for (int i = 0; i < 32; i += 8) {
        int k = k0 + ty + i;
        float v = (k < Dq) ? Kw[(size_t)k * N4H + n0 + tx] : Rw[(size_t)(k - Dq) * N4H + n0 + tx];
        tile[ty + i][tx] = v;
    }
    __syncthreads();
    if (ty < 4) {
        int s = (n0 & 1023) >> 5;
        int q = n0 >> 10;
        int c = k0 >> 5;
        int wlc = q * 32 + tx;
        bf16x8 v;
#pragma unroll
        for (int e = 0; e < 8; ++e) v[e] = (short)f2bf(tile[ty * 8 + e][tx]);
        *(bf16x8*)(Wp + ((((size_t)s * 48 + c) * 128 + wlc) * 4 + ty) * 8) = v;
    }
}

// ---- cast + transpose input to bf16 [T][B][D]
__global__ __launch_bounds__(256) void pack_x(const float* __restrict__ X,
                                              unsigned short* __restrict__ Xb) {
    int gid = blockIdx.x * 256 + threadIdx.x;
    int dc = gid & 63;
    int t = (gid >> 6) & 255;
    int b = gid >> 14;
    const float* src = X + ((size_t)b * Tq + t) * Dq + dc * 8;
    float4 v0 = *(const float4*)src;
    float4 v1 = *(const float4*)(src + 4);
    bf16x8 r;
    r[0] = (short)f2bf(v0.x); r[1] = (short)f2bf(v0.y);
    r[2] = (short)f2bf(v0.z); r[3] = (short)f2bf(v0.w);
    r[4] = (short)f2bf(v1.x); r[5] = (short)f2bf(v1.y);
    r[6] = (short)f2bf(v1.z); r[7] = (short)f2bf(v1.w);
    *(bf16x8*)(Xb + ((size_t)t * Bq + b) * Dq + dc * 8) = r;
}

// ---- zero h buffer 0 + barrier/topology/flag state (re-run every launch)
__global__ __launch_bounds__(256) void init_ws(unsigned short* __restrict__ Hb,
                                               unsigned* __restrict__ bar) {
    int i = blockIdx.x * 256 + threadIdx.x;  // 131072 = h buffer 0
    Hb[i] = 0;
    if (i < 17408) bar[i] = 0;
}

// bar layout (u32, 128B-separated lines):
//   cnt[x]      @ x*32            : per-XCD step counter (plain atomics -> local L2)
//   topo[x]     @ 512 + x*32      : registration tickets (agent, one-time)
//   flag[x][s]  @ 1024 + (x*32+s)*32 : per-wg step flags (1 poller each)
__global__ __launch_bounds__(NTHR, 1) void lstm_persist(
    const unsigned short* __restrict__ Wp,
    const unsigned short* __restrict__ Xb,
    const float* __restrict__ bias,
    unsigned short* __restrict__ Hb,
    const float* __restrict__ dw,
    const float* __restrict__ db,
    float* __restrict__ out,
    unsigned* __restrict__ bar) {
    // LDS: h-chunks 16..27 padded [(cc*128+wlc)*40 + kg*8] = 122,880 B + redbuf 24,576 B
    extern __shared__ unsigned short Wl[];
    float* redbuf = (float*)(Wl + 61440);
    __shared__ float red[16];
    __shared__ int s_topo[4];  // slot, rbase, myxcd, mytot

    const int tid = threadIdx.x;
    const int wave = tid >> 6;
    const int lane = tid & 63;
    const int ug = wave & 3;
    const int kq = wave >> 2;
    const int c16 = lane & 15;
    const int kg = lane >> 4;

    // ---- startup: XCD topology + slot ticket
    if (tid == 0) {
        int xcd;
        asm volatile("s_getreg_b32 %0, hwreg(HW_REG_XCC_ID)" : "=s"(xcd));
        xcd &= 15;
        unsigned slot = __hip_atomic_fetch_add(&bar[512 + xcd * 32], 1u,
                                               __ATOMIC_RELAXED, __HIP_MEMORY_SCOPE_AGENT);
        for (;;) {
            unsigned sum = 0;
            for (int i = 0; i < 16; ++i)
                sum += __hip_atomic_load(&bar[512 + i * 32], __ATOMIC_RELAXED, __HIP_MEMORY_SCOPE_AGENT);
            if (sum == NWG) break;
            __builtin_amdgcn_s_sleep(2);
        }
        int rank = 0, nx = 0, tot = 0;
        for (int i = 0; i < 16; ++i) {
            unsigned v = __hip_atomic_load(&bar[512 + i * 32], __ATOMIC_RELAXED, __HIP_MEMORY_SCOPE_AGENT);
            if (v) { if (i < xcd) rank++; nx++; }
            if (i == xcd) tot = (int)v;
        }
        s_topo[0] = (int)slot;
        s_topo[1] = rank * (Bq / nx);
        s_topo[2] = xcd;
        s_topo[3] = tot;
    }
    __syncthreads();
    const int slot = s_topo[0];
    const int rbase = s_topo[1];
    const int myxcd = s_topo[2];
    const unsigned mytot = (unsigned)s_topo[3];

    const size_t gbase = (size_t)slot * 48 * 4096;

    // ---- load LDS h-chunks 16..27
    for (int it = tid; it < 6144; it += NTHR) {
        int kgx = it & 3;
        int wlcx = (it >> 2) & 127;
        int cc = it >> 9;
        *(bf16x8*)(Wl + ((cc * 128 + wlcx) * 40 + kgx * 8)) =
            *(const bf16x8*)(Wp + gbase + (size_t)(16 + cc) * 4096 + ((size_t)wlcx * 4 + kgx) * 8);
    }

    const int wlc0 = (c16 >> 3) * 32 + ug * 8 + (c16 & 7);
    const int wlc1 = wlc0 + 64;
    const int col0 = (c16 >> 3) * Hq + slot * 32 + ug * 8 + (c16 & 7);
    const int col1 = col0 + 2 * Hq;
    const float bias0 = bias[col0];
    const float bias1 = bias[col1];
    const bool hi = (c16 & 8) != 0;
    const int j = slot * 32 + ug * 8 + (c16 & 7);
    const int arow = rbase + c16;

    // ---- time-invariant h-part B fragments (chunks 28..47 slice) -> registers, ONCE
    bf16x8 pb0[5], pb1[5];
#pragma unroll
    for (int i = 0; i < 5; ++i) {
        int c = kq + 4 * (7 + i);
        const unsigned short* gp = Wp + gbase + (size_t)c * 4096;
        pb0[i] = *(const bf16x8*)(gp + (wlc0 * 4 + kg) * 8);
        pb1[i] = *(const bf16x8*)(gp + (wlc1 * 4 + kg) * 8);
    }

    float creg[4];
#pragma unroll
    for (int i = 0; i < 4; ++i) creg[i] = 0.f;

    __syncthreads();

    // ---- x-part partial accs for t=0 (streamed x-B, overlappable)
    f32x4 xa0 = {0.f, 0.f, 0.f, 0.f};
    f32x4 xa1 = {0.f, 0.f, 0.f, 0.f};
    {
        const unsigned short* xb = Xb + (size_t)arow * Dq + kg * 8;
#pragma unroll
        for (int i = 0; i < 4; ++i) {
            int c = kq + 4 * i;
            bf16x8 A = *(const bf16x8*)(xb + c * 32);
            const unsigned short* gp = Wp + gbase + (size_t)c * 4096;
            bf16x8 B0 = *(const bf16x8*)(gp + (wlc0 * 4 + kg) * 8);
            bf16x8 B1 = *(const bf16x8*)(gp + (wlc1 * 4 + kg) * 8);
            xa0 = __builtin_amdgcn_mfma_f32_16x16x32_bf16(A, B0, xa0, 0, 0, 0);
            xa1 = __builtin_amdgcn_mfma_f32_16x16x32_bf16(A, B1, xa1, 0, 0, 0);
        }
    }

    const unsigned long long cntaddr = (unsigned long long)(bar + myxcd * 32);
    const unsigned long long myflag = (unsigned long long)(bar + 1024 + (myxcd * 32 + slot) * 32);

    for (int t = 0; t < Tq; ++t) {
        const unsigned short* Hcur = Hb + (size_t)t * BHq;
        unsigned short* Hnxt = Hb + (size_t)(t + 1) * BHq;
        const unsigned short* hb = Hcur + (size_t)arow * Hq + kg * 8;

        f32x4 acc0 = xa0, acc1 = xa1;

        // h-part GEMM: reg-held B (chunks 28..47 slice) + LDS B (chunks 16..27 slice)
#pragma unroll
        for (int i = 0; i < 5; ++i) {
            int c = kq + 4 * (7 + i);
            bf16x8 A = *(const bf16x8*)(hb + (c * 32 - Dq));
            acc0 = __builtin_amdgcn_mfma_f32_16x16x32_bf16(A, pb0[i], acc0, 0, 0, 0);
            acc1 = __builtin_amdgcn_mfma_f32_16x16x32_bf16(A, pb1[i], acc1, 0, 0, 0);
        }
#pragma unroll
        for (int i = 4; i < 7; ++i) {
            int c = kq + 4 * i;
            bf16x8 A = *(const bf16x8*)(hb + (c * 32 - Dq));
            const unsigned short* lp = Wl + ((c - 16) * 128) * 40 + kg * 8;
            bf16x8 B0 = *(const bf16x8*)(lp + wlc0 * 40);
            bf16x8 B1 = *(const bf16x8*)(lp + wlc1 * 40);
            acc0 = __builtin_amdgcn_mfma_f32_16x16x32_bf16(A, B0, acc0, 0, 0, 0);
            acc1 = __builtin_amdgcn_mfma_f32_16x16x32_bf16(A, B1, acc1, 0, 0, 0);
        }

        if (kq) {
            float* mr = redbuf + (((kq - 1) * 4 + ug) * 64 + lane) * 8;
            *(f32x4*)&mr[0] = acc0;
            *(f32x4*)&mr[4] = acc1;
        }
        __syncthreads();  // (A)

        if (kq == 0) {
#pragma unroll
            for (int kqi = 1; kqi < 4; ++kqi) {
                const float* rb = redbuf + (((kqi - 1) * 4 + ug) * 64 + lane) * 8;
                acc0 += *(const f32x4*)&rb[0];
                acc1 += *(const f32x4*)&rb[4];
            }
#pragma unroll
            for (int r = 0; r < 4; ++r) {
                float za = acc0[r] + bias0;
                float zb = acc1[r] + bias1;
                float pa = __shfl_xor(za, 8, 64);
                float pb = __shfl_xor(zb, 8, 64);
                float zi = hi ? pa : za;
                float zf = hi ? za : pa;
                float zg = hi ? pb : zb;
                float zo = hi ? zb : pb;
                float gi = sigm(zi);
                float gf = sigm(zf);
                float go = sigm(zo);
                float gg = tanh_f(zg);
                float cn = gf * creg[r] + gi * gg;
                creg[r] = cn;
                float hn = go * tanh_f(cn);
                unsigned hb16 = (unsigned)f2bf(hn);
                unsigned pv = (unsigned)__shfl_xor((int)hb16, 1, 64);
                if (!hi && !(c16 & 1)) {
                    unsigned word = (hb16 & 0xffffu) | (pv << 16);
                    int b = rbase + kg * 4 + r;
                    unsigned long long a = (unsigned long long)(Hnxt + (size_t)b * Hq + j);
                    asm volatile("global_store_dword %0, %1, off sc0" ::"v"(a), "v"(word) : "memory");
                }
            }
        } else if (t + 1 < Tq) {
            const unsigned short* xb = Xb + ((size_t)(t + 1) * Bq + arow) * Dq + kg * 8;
            xa0 = (f32x4){0.f, 0.f, 0.f, 0.f};
            xa1 = (f32x4){0.f, 0.f, 0.f, 0.f};
#pragma unroll
            for (int i = 0; i < 4; ++i) {
                int c = kq + 4 * i;
                bf16x8 A = *(const bf16x8*)(xb + c * 32);
                const unsigned short* gp = Wp + gbase + (size_t)c * 4096;
                bf16x8 B0 = *(const bf16x8*)(gp + (wlc0 * 4 + kg) * 8);
                bf16x8 B1 = *(const bf16x8*)(gp + (wlc1 * 4 + kg) * 8);
                xa0 = __builtin_amdgcn_mfma_f32_16x16x32_bf16(A, B0, xa0, 0, 0, 0);
                xa1 = __builtin_amdgcn_mfma_f32_16x16x32_bf16(A, B1, xa1, 0, 0, 0);
            }
        }

        __syncthreads();  // (B) h sc0-stores drained into local L2

        // ---- arrive: plain atomic add at local L2
        if (tid == 0) {
            asm volatile("global_atomic_add %0, %1, off" ::"v"(cntaddr), "v"(1u) : "memory");
        }

        // kq0 waves: x prefetch for t+1 (overlaps wait)
        if (kq == 0 && t + 1 < Tq) {
            const unsigned short* xb = Xb + ((size_t)(t + 1) * Bq + arow) * Dq + kg * 8;
            xa0 = (f32x4){0.f, 0.f, 0.f, 0.f};
            xa1 = (f32x4){0.f, 0.f, 0.f, 0.f};
#pragma unroll
            for (int i = 0; i < 4; ++i) {
                int c = kq + 4 * i;
                bf16x8 A = *(const bf16x8*)(xb + c * 32);
                const unsigned short* gp = Wp + gbase + (size_t)c * 4096;
                bf16x8 B0 = *(const bf16x8*)(gp + (wlc0 * 4 + kg) * 8);
                bf16x8 B1 = *(const bf16x8*)(gp + (wlc1 * 4 + kg) * 8);
                xa0 = __builtin_amdgcn_mfma_f32_16x16x32_bf16(A, B0, xa0, 0, 0, 0);
                xa1 = __builtin_amdgcn_mfma_f32_16x16x32_bf16(A, B1, xa1, 0, 0, 0);
            }
        }

        // ---- wait: slot0 polls the counter (sole poller), then fans out step
        // flags (sc0 stores); every other wg polls its OWN flag line (1 poller).
        if (tid == 0) {
            if (slot == 0) {
                const unsigned target = mytot * (unsigned)(t + 1);
                for (;;) {
                    unsigned old;
                    asm volatile("global_atomic_add %0, %1, %2, off sc0\n\ts_waitcnt vmcnt(0)"
                                 : "=v"(old)
                                 : "v"(cntaddr), "v"(0u)
                                 : "memory");
                    if (old >= target) break;
                    __builtin_amdgcn_s_sleep(1);
                }
                unsigned stepv = (unsigned)(t + 1);
#pragma unroll
                for (int s = 1; s < 32; ++s) {
                    unsigned long long fa = (unsigned long long)(bar + 1024 + (myxcd * 32 + s) * 32);
                    asm volatile("global_store_dword %0, %1, off sc0" ::"v"(fa), "v"(stepv) : "memory");
                }
            } else {
                for (;;) {
                    unsigned fv;
                    asm volatile("global_atomic_add %0, %1, %2, off sc0\n\ts_waitcnt vmcnt(0)"
                                 : "=v"(fv)
                                 : "v"(myflag), "v"(0u)
                                 : "memory");
                    if (fv >= (unsigned)(t + 1)) break;
                    __builtin_amdgcn_s_sleep(1);
                }
            }
            asm volatile("" ::: "memory");
        }
        __syncthreads();  // (C)
    }

    // ---- dense head: slots 0..15 each handle one local batch row
    if (slot < 16) {
        const int b = rbase + slot;
        const unsigned short* hl = Hb + (size_t)Tq * BHq + (size_t)b * Hq;
        float s = bf2f(hl[tid]) * dw[tid];  // Hq == NTHR
#pragma unroll
        for (int off = 32; off > 0; off >>= 1) s += __shfl_down(s, off, 64);
        if (lane == 0) red[wave] = s;
        __syncthreads();
        if (tid == 0) {
            float tot = db[0];
#pragma unroll
            for (int wv = 0; wv < 16; ++wv) tot += red[wv];
            out[b] = 1.f / (1.f + __expf(-tot));
        }
    }
}

extern "C" void kernel_launch(void* const* d_in, const int* in_sizes, int n_in,
                              void* d_out, int out_size, void* d_ws, size_t ws_size,
                              hipStream_t stream) {
    const float* X = (const float*)d_in[0];
    const float* Kw = (const float*)d_in[1];
    const float* Rw = (const float*)d_in[2];
    const float* bias = (const float*)d_in[3];
    const float* dw = (const float*)d_in[4];
    const float* db = (const float*)d_in[5];
    float* out = (float*)d_out;
    char* ws = (char*)d_ws;

    // workspace layout:
    //   Wp  bf16 fragment-packed [32][48][128][4][8]  @ 0           (12,582,912)
    //   Xb  bf16 [256][128][512]                      @ 12,582,912  (33,554,432)
    //   Hb  bf16 [257][128][1024] rotating            @ 46,137,344  (67,371,008)
    //   bar u32 [17408]                               @ 113,508,352 (69,632)
    unsigned short* Wp = (unsigned short*)(ws);
    unsigned short* Xb = (unsigned short*)(ws + 12582912);
    unsigned short* Hb = (unsigned short*)(ws + 46137344);
    unsigned* bar = (unsigned*)(ws + 113508352);

    pack_w<<<dim3(128, 48), dim3(32, 8), 0, stream>>>(Kw, Rw, Wp);
    pack_x<<<8192, 256, 0, stream>>>(X, Xb);
    init_ws<<<512, 256, 0, stream>>>(Hb, bar);

    size_t lds_bytes = 147456;  // 122,880 weights + 24,576 redbuf
    lstm_persist<<<NWG, NTHR, lds_bytes, stream>>>(Wp, Xb, bias, Hb, dw, db, out, bar);
}

// Round 13
// 3120.593 us; speedup vs baseline: 1.2626x; 1.0009x over previous
//
#include <hip/hip_runtime.h>

#define Bq 128
#define Tq 256
#define Dq 512
#define Hq 1024
#define N4H 4096
#define NWG 256          // 1 wg per CU, 32 per XCD (forced by 147KB LDS)
#define NTHR 1024        // 16 waves: (ug in [0,4)) x (kq in [0,4))
#define BHq (Bq * Hq)

typedef __attribute__((ext_vector_type(8))) short bf16x8;
typedef __attribute__((ext_vector_type(4))) float f32x4;

static __device__ __forceinline__ unsigned short f2bf(float x) {
    unsigned int u = __builtin_bit_cast(unsigned int, x);
    u = (u + 0x7FFFu + ((u >> 16) & 1u)) >> 16;
    return (unsigned short)u;
}
static __device__ __forceinline__ float bf2f(unsigned short h) {
    unsigned int u = ((unsigned int)h) << 16;
    return __builtin_bit_cast(float, u);
}
static __device__ __forceinline__ float sigm(float x) { return 1.f / (1.f + __expf(-x)); }
static __device__ __forceinline__ float tanh_f(float x) { return 2.f / (1.f + __expf(-2.f * x)) - 1.f; }

// ---- pack weights into MFMA-fragment order:
// Wp[s][c][wlc][kg][8e]  (ushort offset = (((s*48+c)*128+wlc)*4+kg)*8)
__global__ __launch_bounds__(256) void pack_w(const float* __restrict__ Kw,
                                              const float* __restrict__ Rw,
                                              unsigned short* __restrict__ Wp) {
    __shared__ float tile[32][33];
    int n0 = blockIdx.x * 32;  // gate-col base
    int k0 = blockIdx.y * 32;  // K base
    int tx = threadIdx.x, ty = threadIdx.y;  // 32 x 8
#pragma unroll
    for (int i = 0; i < 32; i += 8) {
        int k = k0 + ty + i;
        float v = (k < Dq) ? Kw[(size_t)k * N4H + n0 + tx] : Rw[(size_t)(k - Dq) * N4H + n0 + tx];
        tile[ty + i][tx] = v;
    }
    __syncthreads();
    if (ty < 4) {
        int s = (n0 & 1023) >> 5;
        int q = n0 >> 10;
        int c = k0 >> 5;
        int wlc = q * 32 + tx;
        bf16x8 v;
#pragma unroll
        for (int e = 0; e < 8; ++e) v[e] = (short)f2bf(tile[ty * 8 + e][tx]);
        *(bf16x8*)(Wp + ((((size_t)s * 48 + c) * 128 + wlc) * 4 + ty) * 8) = v;
    }
}

// ---- cast + transpose input to bf16 [T][B][D]
__global__ __launch_bounds__(256) void pack_x(const float* __restrict__ X,
                                              unsigned short* __restrict__ Xb) {
    int gid = blockIdx.x * 256 + threadIdx.x;
    int dc = gid & 63;
    int t = (gid >> 6) & 255;
    int b = gid >> 14;
    const float* src = X + ((size_t)b * Tq + t) * Dq + dc * 8;
    float4 v0 = *(const float4*)src;
    float4 v1 = *(const float4*)(src + 4);
    bf16x8 r;
    r[0] = (short)f2bf(v0.x); r[1] = (short)f2bf(v0.y);
    r[2] = (short)f2bf(v0.z); r[3] = (short)f2bf(v0.w);
    r[4] = (short)f2bf(v1.x); r[5] = (short)f2bf(v1.y);
    r[6] = (short)f2bf(v1.z); r[7] = (short)f2bf(v1.w);
    *(bf16x8*)(Xb + ((size_t)t * Bq + b) * Dq + dc * 8) = r;
}

// ---- zero h buffer 0 + barrier/topology/flag state (re-run every launch)
__global__ __launch_bounds__(256) void init_ws(unsigned short* __restrict__ Hb,
                                               unsigned* __restrict__ bar) {
    int i = blockIdx.x * 256 + threadIdx.x;  // 131072 = h buffer 0
    Hb[i] = 0;
    if (i < 17408) bar[i] = 0;
}

// bar layout (u32, 128B-separated lines):
//   cnt[x]      @ x*32            : per-XCD step counter (plain atomics -> local L2)
//   topo[x]     @ 512 + x*32      : registration tickets (agent, one-time)
//   flag[x][s]  @ 1024 + (x*32+s)*32 : per-wg step flags (1 poller each)
__global__ __launch_bounds__(NTHR, 1) void lstm_persist(
    const unsigned short* __restrict__ Wp,
    const unsigned short* __restrict__ Xb,
    const float* __restrict__ bias,
    unsigned short* __restrict__ Hb,
    const float* __restrict__ dw,
    const float* __restrict__ db,
    float* __restrict__ out,
    unsigned* __restrict__ bar) {
    // LDS: h-chunks 16..27 padded [(cc*128+wlc)*40 + kg*8] = 122,880 B + redbuf 24,576 B
    extern __shared__ unsigned short Wl[];
    float* redbuf = (float*)(Wl + 61440);
    __shared__ float red[16];
    __shared__ int s_topo[4];  // slot, rbase, myxcd, mytot

    const int tid = threadIdx.x;
    const int wave = tid >> 6;
    const int lane = tid & 63;
    const int ug = wave & 3;
    const int kq = wave >> 2;
    const int c16 = lane & 15;
    const int kg = lane >> 4;

    // ---- startup: XCD topology + slot ticket
    if (tid == 0) {
        int xcd;
        asm volatile("s_getreg_b32 %0, hwreg(HW_REG_XCC_ID)" : "=s"(xcd));
        xcd &= 15;
        unsigned slot = __hip_atomic_fetch_add(&bar[512 + xcd * 32], 1u,
                                               __ATOMIC_RELAXED, __HIP_MEMORY_SCOPE_AGENT);
        for (;;) {
            unsigned sum = 0;
            for (int i = 0; i < 16; ++i)
                sum += __hip_atomic_load(&bar[512 + i * 32], __ATOMIC_RELAXED, __HIP_MEMORY_SCOPE_AGENT);
            if (sum == NWG) break;
            __builtin_amdgcn_s_sleep(2);
        }
        int rank = 0, nx = 0, tot = 0;
        for (int i = 0; i < 16; ++i) {
            unsigned v = __hip_atomic_load(&bar[512 + i * 32], __ATOMIC_RELAXED, __HIP_MEMORY_SCOPE_AGENT);
            if (v) { if (i < xcd) rank++; nx++; }
            if (i == xcd) tot = (int)v;
        }
        s_topo[0] = (int)slot;
        s_topo[1] = rank * (Bq / nx);
        s_topo[2] = xcd;
        s_topo[3] = tot;
    }
    __syncthreads();
    const int slot = s_topo[0];
    const int rbase = s_topo[1];
    const int myxcd = s_topo[2];
    const unsigned mytot = (unsigned)s_topo[3];

    const size_t gbase = (size_t)slot * 48 * 4096;

    // ---- load LDS h-chunks 16..27
    for (int it = tid; it < 6144; it += NTHR) {
        int kgx = it & 3;
        int wlcx = (it >> 2) & 127;
        int cc = it >> 9;
        *(bf16x8*)(Wl + ((cc * 128 + wlcx) * 40 + kgx * 8)) =
            *(const bf16x8*)(Wp + gbase + (size_t)(16 + cc) * 4096 + ((size_t)wlcx * 4 + kgx) * 8);
    }

    const int wlc0 = (c16 >> 3) * 32 + ug * 8 + (c16 & 7);
    const int wlc1 = wlc0 + 64;
    const int col0 = (c16 >> 3) * Hq + slot * 32 + ug * 8 + (c16 & 7);
    const int col1 = col0 + 2 * Hq;
    const float bias0 = bias[col0];
    const float bias1 = bias[col1];
    const bool hi = (c16 & 8) != 0;
    const int j = slot * 32 + ug * 8 + (c16 & 7);
    const int arow = rbase + c16;

    // ---- time-invariant h-part B fragments (chunks 28..47 slice) -> registers, ONCE
    bf16x8 pb0[5], pb1[5];
#pragma unroll
    for (int i = 0; i < 5; ++i) {
        int c = kq + 4 * (7 + i);
        const unsigned short* gp = Wp + gbase + (size_t)c * 4096;
        pb0[i] = *(const bf16x8*)(gp + (wlc0 * 4 + kg) * 8);
        pb1[i] = *(const bf16x8*)(gp + (wlc1 * 4 + kg) * 8);
    }

    float creg[4];
#pragma unroll
    for (int i = 0; i < 4; ++i) creg[i] = 0.f;

    __syncthreads();

    // ---- x-part partial accs for t=0 (streamed x-B, overlappable)
    f32x4 xa0 = {0.f, 0.f, 0.f, 0.f};
    f32x4 xa1 = {0.f, 0.f, 0.f, 0.f};
    {
        const unsigned short* xb = Xb + (size_t)arow * Dq + kg * 8;
#pragma unroll
        for (int i = 0; i < 4; ++i) {
            int c = kq + 4 * i;
            bf16x8 A = *(const bf16x8*)(xb + c * 32);
            const unsigned short* gp = Wp + gbase + (size_t)c * 4096;
            bf16x8 B0 = *(const bf16x8*)(gp + (wlc0 * 4 + kg) * 8);
            bf16x8 B1 = *(const bf16x8*)(gp + (wlc1 * 4 + kg) * 8);
            xa0 = __builtin_amdgcn_mfma_f32_16x16x32_bf16(A, B0, xa0, 0, 0, 0);
            xa1 = __builtin_amdgcn_mfma_f32_16x16x32_bf16(A, B1, xa1, 0, 0, 0);
        }
    }

    const unsigned long long cntaddr = (unsigned long long)(bar + myxcd * 32);
    const unsigned long long myflag = (unsigned long long)(bar + 1024 + (myxcd * 32 + slot) * 32);

    for (int t = 0; t < Tq; ++t) {
        const unsigned short* Hcur = Hb + (size_t)t * BHq;
        unsigned short* Hnxt = Hb + (size_t)(t + 1) * BHq;
        const unsigned short* hb = Hcur + (size_t)arow * Hq + kg * 8;

        f32x4 acc0 = xa0, acc1 = xa1;

        // h-part GEMM: reg-held B (chunks 28..47 slice) + LDS B (chunks 16..27 slice)
#pragma unroll
        for (int i = 0; i < 5; ++i) {
            int c = kq + 4 * (7 + i);
            bf16x8 A = *(const bf16x8*)(hb + (c * 32 - Dq));
            acc0 = __builtin_amdgcn_mfma_f32_16x16x32_bf16(A, pb0[i], acc0, 0, 0, 0);
            acc1 = __builtin_amdgcn_mfma_f32_16x16x32_bf16(A, pb1[i], acc1, 0, 0, 0);
        }
#pragma unroll
        for (int i = 4; i < 7; ++i) {
            int c = kq + 4 * i;
            bf16x8 A = *(const bf16x8*)(hb + (c * 32 - Dq));
            const unsigned short* lp = Wl + ((c - 16) * 128) * 40 + kg * 8;
            bf16x8 B0 = *(const bf16x8*)(lp + wlc0 * 40);
            bf16x8 B1 = *(const bf16x8*)(lp + wlc1 * 40);
            acc0 = __builtin_amdgcn_mfma_f32_16x16x32_bf16(A, B0, acc0, 0, 0, 0);
            acc1 = __builtin_amdgcn_mfma_f32_16x16x32_bf16(A, B1, acc1, 0, 0, 0);
        }

        if (kq) {
            float* mr = redbuf + (((kq - 1) * 4 + ug) * 64 + lane) * 8;
            *(f32x4*)&mr[0] = acc0;
            *(f32x4*)&mr[4] = acc1;
        }
        __syncthreads();  // (A)

        if (kq == 0) {
#pragma unroll
            for (int kqi = 1; kqi < 4; ++kqi) {
                const float* rb = redbuf + (((kqi - 1) * 4 + ug) * 64 + lane) * 8;
                acc0 += *(const f32x4*)&rb[0];
                acc1 += *(const f32x4*)&rb[4];
            }
#pragma unroll
            for (int r = 0; r < 4; ++r) {
                float za = acc0[r] + bias0;
                float zb = acc1[r] + bias1;
                float pa = __shfl_xor(za, 8, 64);
                float pb = __shfl_xor(zb, 8, 64);
                float zi = hi ? pa : za;
                float zf = hi ? za : pa;
                float zg = hi ? pb : zb;
                float zo = hi ? zb : pb;
                float gi = sigm(zi);
                float gf = sigm(zf);
                float go = sigm(zo);
                float gg = tanh_f(zg);
                float cn = gf * creg[r] + gi * gg;
                creg[r] = cn;
                float hn = go * tanh_f(cn);
                unsigned hb16 = (unsigned)f2bf(hn);
                unsigned pv = (unsigned)__shfl_xor((int)hb16, 1, 64);
                if (!hi && !(c16 & 1)) {
                    unsigned word = (hb16 & 0xffffu) | (pv << 16);
                    int b = rbase + kg * 4 + r;
                    unsigned long long a = (unsigned long long)(Hnxt + (size_t)b * Hq + j);
                    asm volatile("global_store_dword %0, %1, off sc0" ::"v"(a), "v"(word) : "memory");
                }
            }
        } else if (t + 1 < Tq) {
            const unsigned short* xb = Xb + ((size_t)(t + 1) * Bq + arow) * Dq + kg * 8;
            xa0 = (f32x4){0.f, 0.f, 0.f, 0.f};
            xa1 = (f32x4){0.f, 0.f, 0.f, 0.f};
#pragma unroll
            for (int i = 0; i < 4; ++i) {
                int c = kq + 4 * i;
                bf16x8 A = *(const bf16x8*)(xb + c * 32);
                const unsigned short* gp = Wp + gbase + (size_t)c * 4096;
                bf16x8 B0 = *(const bf16x8*)(gp + (wlc0 * 4 + kg) * 8);
                bf16x8 B1 = *(const bf16x8*)(gp + (wlc1 * 4 + kg) * 8);
                xa0 = __builtin_amdgcn_mfma_f32_16x16x32_bf16(A, B0, xa0, 0, 0, 0);
                xa1 = __builtin_amdgcn_mfma_f32_16x16x32_bf16(A, B1, xa1, 0, 0, 0);
            }
        }

        __syncthreads();  // (B) h sc0-stores drained into local L2

        // ---- arrive: plain atomic add at local L2
        if (tid == 0) {
            asm volatile("global_atomic_add %0, %1, off" ::"v"(cntaddr), "v"(1u) : "memory");
        }

        // kq0 waves: x prefetch for t+1 (overlaps wait)
        if (kq == 0 && t + 1 < Tq) {
            const unsigned short* xb = Xb + ((size_t)(t + 1) * Bq + arow) * Dq + kg * 8;
            xa0 = (f32x4){0.f, 0.f, 0.f, 0.f};
            xa1 = (f32x4){0.f, 0.f, 0.f, 0.f};
#pragma unroll
            for (int i = 0; i < 4; ++i) {
                int c = kq + 4 * i;
                bf16x8 A = *(const bf16x8*)(xb + c * 32);
                const unsigned short* gp = Wp + gbase + (size_t)c * 4096;
                bf16x8 B0 = *(const bf16x8*)(gp + (wlc0 * 4 + kg) * 8);
                bf16x8 B1 = *(const bf16x8*)(gp + (wlc1 * 4 + kg) * 8);
                xa0 = __builtin_amdgcn_mfma_f32_16x16x32_bf16(A, B0, xa0, 0, 0, 0);
                xa1 = __builtin_amdgcn_mfma_f32_16x16x32_bf16(A, B1, xa1, 0, 0, 0);
            }
        }

        // ---- wait: slot0 polls the counter (sole poller), then fans out step
        // flags (sc0 stores); every other wg polls its OWN flag line (1 poller).
        if (tid == 0) {
            if (slot == 0) {
                const unsigned target = mytot * (unsigned)(t + 1);
                for (;;) {
                    unsigned old;
                    asm volatile("global_atomic_add %0, %1, %2, off sc0\n\ts_waitcnt vmcnt(0)"
                                 : "=v"(old)
                                 : "v"(cntaddr), "v"(0u)
                                 : "memory");
                    if (old >= target) break;
                    __builtin_amdgcn_s_sleep(1);
                }
                unsigned stepv = (unsigned)(t + 1);
#pragma unroll
                for (int s = 1; s < 32; ++s) {
                    unsigned long long fa = (unsigned long long)(bar + 1024 + (myxcd * 32 + s) * 32);
                    asm volatile("global_store_dword %0, %1, off sc0" ::"v"(fa), "v"(stepv) : "memory");
                }
            } else {
                for (;;) {
                    unsigned fv;
                    asm volatile("global_atomic_add %0, %1, %2, off sc0\n\ts_waitcnt vmcnt(0)"
                                 : "=v"(fv)
                                 : "v"(myflag), "v"(0u)
                                 : "memory");
                    if (fv >= (unsigned)(t + 1)) break;
                    __builtin_amdgcn_s_sleep(1);
                }
            }
            asm volatile("" ::: "memory");
        }
        __syncthreads();  // (C)
    }

    // ---- dense head: slots 0..15 each handle one local batch row
    if (slot < 16) {
        const int b = rbase + slot;
        const unsigned short* hl = Hb + (size_t)Tq * BHq + (size_t)b * Hq;
        float s = bf2f(hl[tid]) * dw[tid];  // Hq == NTHR
#pragma unroll
        for (int off = 32; off > 0; off >>= 1) s += __shfl_down(s, off, 64);
        if (lane == 0) red[wave] = s;
        __syncthreads();
        if (tid == 0) {
            float tot = db[0];
#pragma unroll
            for (int wv = 0; wv < 16; ++wv) tot += red[wv];
            out[b] = 1.f / (1.f + __expf(-tot));
        }
    }
}

extern "C" void kernel_launch(void* const* d_in, const int* in_sizes, int n_in,
                              void* d_out, int out_size, void* d_ws, size_t ws_size,
                              hipStream_t stream) {
    const float* X = (const float*)d_in[0];
    const float* Kw = (const float*)d_in[1];
    const float* Rw = (const float*)d_in[2];
    const float* bias = (const float*)d_in[3];
    const float* dw = (const float*)d_in[4];
    const float* db = (const float*)d_in[5];
    float* out = (float*)d_out;
    char* ws = (char*)d_ws;

    // workspace layout:
    //   Wp  bf16 fragment-packed [32][48][128][4][8]  @ 0           (12,582,912)
    //   Xb  bf16 [256][128][512]                      @ 12,582,912  (33,554,432)
    //   Hb  bf16 [257][128][1024] rotating            @ 46,137,344  (67,371,008)
    //   bar u32 [17408]                               @ 113,508,352 (69,632)
    unsigned short* Wp = (unsigned short*)(ws);
    unsigned short* Xb = (unsigned short*)(ws + 12582912);
    unsigned short* Hb = (unsigned short*)(ws + 46137344);
    unsigned* bar = (unsigned*)(ws + 113508352);

    pack_w<<<dim3(128, 48), dim3(32, 8), 0, stream>>>(Kw, Rw, Wp);
    pack_x<<<8192, 256, 0, stream>>>(X, Xb);
    init_ws<<<512, 256, 0, stream>>>(Hb, bar);

    size_t lds_bytes = 147456;  // 122,880 weights + 24,576 redbuf
    lstm_persist<<<NWG, NTHR, lds_bytes, stream>>>(Wp, Xb, bias, Hb, dw, db, out, bar);
}